// Round 2
// baseline (274.812 us; speedup 1.0000x reference)
//
#include <hip/hip_runtime.h>

typedef short short8 __attribute__((ext_vector_type(8)));
typedef float f32x4 __attribute__((ext_vector_type(4)));

#define DEVFN __device__ __forceinline__

DEVFN unsigned short f2bf(float f) {
  union { float f; unsigned int i; } c; c.f = f;
  unsigned int r = c.i + 0x7FFFu + ((c.i >> 16) & 1u);
  return (unsigned short)(r >> 16);
}
DEVFN short f2bfs(float f) { return (short)f2bf(f); }

static constexpr int Bn  = 2;
static constexpr int L   = 8000;
static constexpr int BL  = Bn * L;     // 16000
static constexpr int DIM = 128;
static constexpr int DI  = 256;        // d_inner
static constexpr int DS  = 16;         // d_state
static constexpr int CLEN = 80;        // chunk length
static constexpr int NCH  = 100;       // chunks per sequence

// ---------------------------------------------------------------- K1: LN + in_proj
// per wave: 16 rows (bl) x 512 cols. A = LN(x) in-register (K=dim=128 = 4 frags),
// B = in_proj_w rows, f32 loads converted to bf16 fragments in-register.
__global__ __launch_bounds__(256) void k_ln_inproj(
    const float* __restrict__ x,      // (B,128,L)
    const float* __restrict__ gamma,
    const float* __restrict__ beta,
    const float* __restrict__ W,      // (512,128)
    float* __restrict__ xi,           // (BL,256)
    float* __restrict__ z)            // (BL,256)
{
  const int wid  = (blockIdx.x * blockDim.x + threadIdx.x) >> 6;   // 0..999
  const int lane = threadIdx.x & 63;
  const int m  = lane & 15;
  const int gq = lane >> 4;
  const int bl0 = wid * 16;
  const int bl  = bl0 + m;
  const int b   = (bl >= L) ? 1 : 0;
  const int l   = bl - b * L;
  const float* xb = x + (size_t)b * DIM * L + l;

  float v[32];
  float s = 0.f, s2 = 0.f;
  #pragma unroll
  for (int f = 0; f < 4; ++f)
    #pragma unroll
    for (int j = 0; j < 8; ++j) {
      int k = f * 32 + gq * 8 + j;
      float t = xb[(size_t)k * L];
      v[f * 8 + j] = t; s += t; s2 += t * t;
    }
  s  += __shfl_xor(s, 16);  s  += __shfl_xor(s, 32);
  s2 += __shfl_xor(s2, 16); s2 += __shfl_xor(s2, 32);
  float mu   = s * (1.f / 128.f);
  float var  = s2 * (1.f / 128.f) - mu * mu;
  float rstd = rsqrtf(var + 1e-5f);

  short8 a[4];
  #pragma unroll
  for (int f = 0; f < 4; ++f)
    #pragma unroll
    for (int j = 0; j < 8; ++j) {
      int k = f * 32 + gq * 8 + j;
      float xn = (v[f * 8 + j] - mu) * rstd * gamma[k] + beta[k];
      a[f][j] = f2bfs(xn);
    }

  for (int nt = 0; nt < 32; ++nt) {
    int n0 = nt * 16;
    const float* wr = W + (size_t)(n0 + m) * DIM + gq * 8;
    f32x4 acc = {0.f, 0.f, 0.f, 0.f};
    #pragma unroll
    for (int f = 0; f < 4; ++f) {
      short8 bfr;
      #pragma unroll
      for (int j = 0; j < 8; ++j) bfr[j] = f2bfs(wr[f * 32 + j]);
      acc = __builtin_amdgcn_mfma_f32_16x16x32_bf16(a[f], bfr, acc, 0, 0, 0);
    }
    int ng = n0 + m;
    float* dst = (n0 < DI) ? xi : z;
    int nn = (n0 < DI) ? ng : (ng - DI);
    #pragma unroll
    for (int r = 0; r < 4; ++r) {
      int row = bl0 + gq * 4 + r;
      dst[(size_t)row * DI + nn] = acc[r];
    }
  }
}

// ---------------------------------------------------------------- K2: causal depthwise conv + SiLU
__global__ __launch_bounds__(256) void k_conv(
    const float* __restrict__ xi,
    const float* __restrict__ cw,   // (256,1,4)
    const float* __restrict__ cb,
    float* __restrict__ xc)
{
  int idx = blockIdx.x * 256 + threadIdx.x;   // bl*256 + d
  int d  = idx & 255;
  int bl = idx >> 8;
  int b  = (bl >= L) ? 1 : 0;
  int l  = bl - b * L;
  float acc = cb[d];
  #pragma unroll
  for (int t = 0; t < 4; ++t) {
    int ll = l - 3 + t;
    if (ll >= 0)
      acc += cw[d * 4 + t] * xi[((size_t)(b * L + ll)) * DI + d];
  }
  float sig = 1.f / (1.f + __expf(-acc));
  xc[idx] = acc * sig;
}

// ---------------------------------------------------------------- K3: x_proj (N=40, padded to 48)
__global__ __launch_bounds__(256) void k_xproj(
    const float* __restrict__ xc,
    const float* __restrict__ W,    // (40,256)
    float* __restrict__ dtr,        // (BL,8)
    float* __restrict__ Bm,         // (BL,16)
    float* __restrict__ Cm)         // (BL,16)
{
  const int wid  = (blockIdx.x * blockDim.x + threadIdx.x) >> 6;
  const int lane = threadIdx.x & 63;
  const int m = lane & 15, gq = lane >> 4;
  const int bl0 = wid * 16;
  const float* ap = xc + (size_t)(bl0 + m) * DI + gq * 8;
  short8 a[8];
  #pragma unroll
  for (int f = 0; f < 8; ++f)
    #pragma unroll
    for (int j = 0; j < 8; ++j) a[f][j] = f2bfs(ap[f * 32 + j]);

  #pragma unroll
  for (int nt = 0; nt < 3; ++nt) {
    int n0 = nt * 16;
    int n  = n0 + m;
    f32x4 acc = {0.f, 0.f, 0.f, 0.f};
    const float* wr = W + (size_t)n * DI + gq * 8;
    #pragma unroll
    for (int f = 0; f < 8; ++f) {
      short8 bfr = {0,0,0,0,0,0,0,0};
      if (n < 40)
        #pragma unroll
        for (int j = 0; j < 8; ++j) bfr[j] = f2bfs(wr[f * 32 + j]);
      acc = __builtin_amdgcn_mfma_f32_16x16x32_bf16(a[f], bfr, acc, 0, 0, 0);
    }
    #pragma unroll
    for (int r = 0; r < 4; ++r) {
      int row = bl0 + gq * 4 + r;
      if (n < 8)       dtr[(size_t)row * 8  + n]        = acc[r];
      else if (n < 24) Bm [(size_t)row * 16 + (n - 8)]  = acc[r];
      else if (n < 40) Cm [(size_t)row * 16 + (n - 24)] = acc[r];
    }
  }
}

// ---------------------------------------------------------------- K4: dt_proj + softplus
__global__ __launch_bounds__(256) void k_dtproj(
    const float* __restrict__ dtr,
    const float* __restrict__ Wd,   // (256,8)
    const float* __restrict__ bd,
    float* __restrict__ dtf)        // (BL,256)
{
  int idx = blockIdx.x * 256 + threadIdx.x;
  int d  = idx & 255;
  int bl = idx >> 8;
  float acc = bd[d];
  const float* r = dtr + (size_t)bl * 8;
  #pragma unroll
  for (int j = 0; j < 8; ++j) acc += r[j] * Wd[d * 8 + j];
  float sp = (acc > 20.f) ? acc : log1pf(__expf(acc));
  dtf[idx] = sp;
}

// ---------------------------------------------------------------- K5: scan pass A (per-chunk P, S)
__global__ __launch_bounds__(256) void k_scanA(
    const float* __restrict__ dtf,
    const float* __restrict__ xc,
    const float* __restrict__ Bm,
    const float* __restrict__ alog,  // (256,16)
    float* __restrict__ Pc, float* __restrict__ Sc)
{
  int t  = blockIdx.x * 256 + threadIdx.x;    // (c*2+b)*4096 + ch
  int ch = t & 4095;
  int cb = t >> 12;
  int b  = cb & 1;
  int c  = cb >> 1;
  int d  = ch >> 4, n = ch & 15;
  const float A2 = -__expf(alog[ch]) * 1.4426950408889634f;
  size_t blbase = (size_t)b * L + (size_t)c * CLEN;
  float h = 0.f, P = 1.f;
  for (int tt = 0; tt < CLEN; ++tt) {
    size_t bl = blbase + tt;
    float dt = dtf[bl * DI + d];
    float u  = dt * xc[bl * DI + d];
    float dA = exp2f(dt * A2);
    h = dA * h + u * Bm[bl * DS + n];
    P *= dA;
  }
  Pc[t] = P;
  Sc[t] = h;
}

// ---------------------------------------------------------------- K6: scan pass B (chunk-level scan)
__global__ __launch_bounds__(256) void k_scanB(
    const float* __restrict__ Pc, const float* __restrict__ Sc, float* __restrict__ Hc)
{
  int t = blockIdx.x * 256 + threadIdx.x;     // b*4096 + ch, < 8192
  float h = 0.f;
  for (int c = 0; c < NCH; ++c) {
    int idx = c * 8192 + t;
    Hc[idx] = h;
    h = Pc[idx] * h + Sc[idx];
  }
}

// ---------------------------------------------------------------- K7: scan pass C (+ gate fuse)
__global__ __launch_bounds__(256) void k_scanC(
    const float* __restrict__ dtf,
    const float* __restrict__ xc,
    const float* __restrict__ Bm,
    const float* __restrict__ Cm,
    const float* __restrict__ alog,
    const float* __restrict__ Dp,
    const float* __restrict__ z,
    const float* __restrict__ Hc,
    float* __restrict__ y)            // (BL,256)
{
  int t  = blockIdx.x * 256 + threadIdx.x;
  int ch = t & 4095;
  int cb = t >> 12;
  int b  = cb & 1;
  int c  = cb >> 1;
  int d  = ch >> 4, n = ch & 15;
  const float A2 = -__expf(alog[ch]) * 1.4426950408889634f;
  size_t blbase = (size_t)b * L + (size_t)c * CLEN;
  float h  = Hc[(size_t)c * 8192 + b * 4096 + ch];
  float Dv = Dp[d];
  for (int tt = 0; tt < CLEN; ++tt) {
    size_t bl = blbase + tt;
    float dt  = dtf[bl * DI + d];
    float xcf = xc[bl * DI + d];
    float dA  = exp2f(dt * A2);
    h = dA * h + (dt * xcf) * Bm[bl * DS + n];
    float p = h * Cm[bl * DS + n];
    p += __shfl_xor(p, 1);
    p += __shfl_xor(p, 2);
    p += __shfl_xor(p, 4);
    p += __shfl_xor(p, 8);
    if (n == 0) {
      float zf  = z[bl * DI + d];
      float sil = zf / (1.f + __expf(-zf));
      y[bl * DI + d] = (p + xcf * Dv) * sil;
    }
  }
}

// ---------------------------------------------------------------- K8: out_proj + residual (out is (B,128,L))
// Swapped operands: A = out_proj_w (rows=c), B = y^T (cols=l) so stores along l are contiguous.
__global__ __launch_bounds__(256) void k_outproj(
    const float* __restrict__ y,
    const float* __restrict__ W,    // (128,256)
    const float* __restrict__ x,    // (B,128,L)
    float* __restrict__ out)        // (B,128,L)
{
  const int wid  = (blockIdx.x * blockDim.x + threadIdx.x) >> 6;   // 0..999
  const int lane = threadIdx.x & 63;
  const int m = lane & 15, gq = lane >> 4;
  const int bl0 = wid * 16;
  const int b = (bl0 >= L) ? 1 : 0;
  const int lbase = bl0 - b * L;

  const float* bp = y + (size_t)(bl0 + m) * DI + gq * 8;
  short8 bfrag[8];
  #pragma unroll
  for (int f = 0; f < 8; ++f)
    #pragma unroll
    for (int j = 0; j < 8; ++j) bfrag[f][j] = f2bfs(bp[f * 32 + j]);

  for (int ct = 0; ct < 8; ++ct) {
    int c0 = ct * 16;
    const float* ap = W + (size_t)(c0 + m) * DI + gq * 8;
    f32x4 acc = {0.f, 0.f, 0.f, 0.f};
    #pragma unroll
    for (int f = 0; f < 8; ++f) {
      short8 a;
      #pragma unroll
      for (int j = 0; j < 8; ++j) a[j] = f2bfs(ap[f * 32 + j]);
      acc = __builtin_amdgcn_mfma_f32_16x16x32_bf16(a, bfrag[f], acc, 0, 0, 0);
    }
    #pragma unroll
    for (int r = 0; r < 4; ++r) {
      int cc = c0 + gq * 4 + r;
      size_t o = ((size_t)b * DIM + cc) * L + lbase + m;
      out[o] = x[o] + acc[r];
    }
  }
}

// ----------------------------------------------------------------
extern "C" void kernel_launch(void* const* d_in, const int* in_sizes, int n_in,
                              void* d_out, int out_size, void* d_ws, size_t ws_size,
                              hipStream_t stream)
{
  const float* x      = (const float*)d_in[0];
  const float* gamma  = (const float*)d_in[1];
  const float* beta   = (const float*)d_in[2];
  const float* inW    = (const float*)d_in[3];
  const float* convW  = (const float*)d_in[4];
  const float* convB  = (const float*)d_in[5];
  const float* xprojW = (const float*)d_in[6];
  const float* dtW    = (const float*)d_in[7];
  const float* dtB    = (const float*)d_in[8];
  const float* Alog   = (const float*)d_in[9];
  const float* Dp     = (const float*)d_in[10];
  const float* outW   = (const float*)d_in[11];
  float* out = (float*)d_out;

  char* ws = (char*)d_ws;
  float* xi  = (float*)(ws + 0);            // BL*256 f32 = 16,384,000
  float* z   = (float*)(ws + 16384000);     // BL*256 f32
  float* xc  = (float*)(ws + 32768000);     // BL*256 f32
  float* dtf = (float*)(ws + 49152000);     // BL*256 f32
  float* dtr = (float*)(ws + 65536000);     // BL*8  f32 =    512,000
  float* Bm  = (float*)(ws + 66048000);     // BL*16 f32 =  1,024,000
  float* Cm  = (float*)(ws + 67072000);     // BL*16 f32 =  1,024,000
  float* yb  = (float*)(ws + 68096000);     // BL*256 f32 = 16,384,000
  float* Pc  = (float*)(ws + 84480000);     // 100*8192 f32 = 3,276,800
  float* Sc  = (float*)(ws + 87756800);
  float* Hc  = (float*)(ws + 91033600);     // end 94,310,400 B

  hipLaunchKernelGGL(k_ln_inproj, dim3(250),   dim3(256), 0, stream, x, gamma, beta, inW, xi, z);
  hipLaunchKernelGGL(k_conv,      dim3(16000), dim3(256), 0, stream, xi, convW, convB, xc);
  hipLaunchKernelGGL(k_xproj,     dim3(250),   dim3(256), 0, stream, xc, xprojW, dtr, Bm, Cm);
  hipLaunchKernelGGL(k_dtproj,    dim3(16000), dim3(256), 0, stream, dtr, dtW, dtB, dtf);
  hipLaunchKernelGGL(k_scanA,     dim3(3200),  dim3(256), 0, stream, dtf, xc, Bm, Alog, Pc, Sc);
  hipLaunchKernelGGL(k_scanB,     dim3(32),    dim3(256), 0, stream, Pc, Sc, Hc);
  hipLaunchKernelGGL(k_scanC,     dim3(3200),  dim3(256), 0, stream, dtf, xc, Bm, Cm, Alog, Dp, z, Hc, yb);
  hipLaunchKernelGGL(k_outproj,   dim3(250),   dim3(256), 0, stream, yb, outW, x, out);
}

// Round 3
// 197.744 us; speedup vs baseline: 1.3897x; 1.3897x over previous
//
#include <hip/hip_runtime.h>

typedef short short8 __attribute__((ext_vector_type(8)));
typedef float f32x4 __attribute__((ext_vector_type(4)));

#define DEVFN __device__ __forceinline__

DEVFN unsigned short f2bf(float f) {
  union { float f; unsigned int i; } c; c.f = f;
  unsigned int r = c.i + 0x7FFFu + ((c.i >> 16) & 1u);
  return (unsigned short)(r >> 16);
}
DEVFN short f2bfs(float f) { return (short)f2bf(f); }

static constexpr int Bn  = 2;
static constexpr int L   = 8000;
static constexpr int BL  = Bn * L;     // 16000
static constexpr int DIM = 128;
static constexpr int DI  = 256;        // d_inner
static constexpr int DS  = 16;         // d_state
static constexpr int CLEN = 40;        // chunk length
static constexpr int NCH  = 200;       // chunks per sequence (2*NCH = 400 blocks)

// ---------------------------------------------------------------- K1: LN + in_proj
__global__ __launch_bounds__(256) void k_ln_inproj(
    const float* __restrict__ x,      // (B,128,L)
    const float* __restrict__ gamma,
    const float* __restrict__ beta,
    const float* __restrict__ W,      // (512,128)
    float* __restrict__ xi,           // (BL,256)
    float* __restrict__ z)            // (BL,256)
{
  const int wid  = (blockIdx.x * blockDim.x + threadIdx.x) >> 6;   // 0..999
  const int lane = threadIdx.x & 63;
  const int m  = lane & 15;
  const int gq = lane >> 4;
  const int bl0 = wid * 16;
  const int bl  = bl0 + m;
  const int b   = (bl >= L) ? 1 : 0;
  const int l   = bl - b * L;
  const float* xb = x + (size_t)b * DIM * L + l;

  float v[32];
  float s = 0.f, s2 = 0.f;
  #pragma unroll
  for (int f = 0; f < 4; ++f)
    #pragma unroll
    for (int j = 0; j < 8; ++j) {
      int k = f * 32 + gq * 8 + j;
      float t = xb[(size_t)k * L];
      v[f * 8 + j] = t; s += t; s2 += t * t;
    }
  s  += __shfl_xor(s, 16);  s  += __shfl_xor(s, 32);
  s2 += __shfl_xor(s2, 16); s2 += __shfl_xor(s2, 32);
  float mu   = s * (1.f / 128.f);
  float var  = s2 * (1.f / 128.f) - mu * mu;
  float rstd = rsqrtf(var + 1e-5f);

  short8 a[4];
  #pragma unroll
  for (int f = 0; f < 4; ++f)
    #pragma unroll
    for (int j = 0; j < 8; ++j) {
      int k = f * 32 + gq * 8 + j;
      float xn = (v[f * 8 + j] - mu) * rstd * gamma[k] + beta[k];
      a[f][j] = f2bfs(xn);
    }

  for (int nt = 0; nt < 32; ++nt) {
    int n0 = nt * 16;
    const float* wr = W + (size_t)(n0 + m) * DIM + gq * 8;
    f32x4 acc = {0.f, 0.f, 0.f, 0.f};
    #pragma unroll
    for (int f = 0; f < 4; ++f) {
      short8 bfr;
      #pragma unroll
      for (int j = 0; j < 8; ++j) bfr[j] = f2bfs(wr[f * 32 + j]);
      acc = __builtin_amdgcn_mfma_f32_16x16x32_bf16(a[f], bfr, acc, 0, 0, 0);
    }
    int ng = n0 + m;
    float* dst = (n0 < DI) ? xi : z;
    int nn = (n0 < DI) ? ng : (ng - DI);
    #pragma unroll
    for (int r = 0; r < 4; ++r) {
      int row = bl0 + gq * 4 + r;
      dst[(size_t)row * DI + nn] = acc[r];
    }
  }
}

// ---------------------------------------------------------------- K2: causal depthwise conv + SiLU
__global__ __launch_bounds__(256) void k_conv(
    const float* __restrict__ xi,
    const float* __restrict__ cw,   // (256,1,4)
    const float* __restrict__ cb,
    float* __restrict__ xc)
{
  int idx = blockIdx.x * 256 + threadIdx.x;   // bl*256 + d
  int d  = idx & 255;
  int bl = idx >> 8;
  int b  = (bl >= L) ? 1 : 0;
  int l  = bl - b * L;
  float acc = cb[d];
  #pragma unroll
  for (int t = 0; t < 4; ++t) {
    int ll = l - 3 + t;
    if (ll >= 0)
      acc += cw[d * 4 + t] * xi[((size_t)(b * L + ll)) * DI + d];
  }
  float sig = 1.f / (1.f + __expf(-acc));
  xc[idx] = acc * sig;
}

// ---------------------------------------------------------------- K3: x_proj (N=40, padded to 48)
__global__ __launch_bounds__(256) void k_xproj(
    const float* __restrict__ xc,
    const float* __restrict__ W,    // (40,256)
    float* __restrict__ dtr,        // (BL,8)
    float* __restrict__ Bm,         // (BL,16)
    float* __restrict__ Cm)         // (BL,16)
{
  const int wid  = (blockIdx.x * blockDim.x + threadIdx.x) >> 6;
  const int lane = threadIdx.x & 63;
  const int m = lane & 15, gq = lane >> 4;
  const int bl0 = wid * 16;
  const float* ap = xc + (size_t)(bl0 + m) * DI + gq * 8;
  short8 a[8];
  #pragma unroll
  for (int f = 0; f < 8; ++f)
    #pragma unroll
    for (int j = 0; j < 8; ++j) a[f][j] = f2bfs(ap[f * 32 + j]);

  #pragma unroll
  for (int nt = 0; nt < 3; ++nt) {
    int n0 = nt * 16;
    int n  = n0 + m;
    f32x4 acc = {0.f, 0.f, 0.f, 0.f};
    const float* wr = W + (size_t)n * DI + gq * 8;
    #pragma unroll
    for (int f = 0; f < 8; ++f) {
      short8 bfr = {0,0,0,0,0,0,0,0};
      if (n < 40)
        #pragma unroll
        for (int j = 0; j < 8; ++j) bfr[j] = f2bfs(wr[f * 32 + j]);
      acc = __builtin_amdgcn_mfma_f32_16x16x32_bf16(a[f], bfr, acc, 0, 0, 0);
    }
    #pragma unroll
    for (int r = 0; r < 4; ++r) {
      int row = bl0 + gq * 4 + r;
      if (n < 8)       dtr[(size_t)row * 8  + n]        = acc[r];
      else if (n < 24) Bm [(size_t)row * 16 + (n - 8)]  = acc[r];
      else if (n < 40) Cm [(size_t)row * 16 + (n - 24)] = acc[r];
    }
  }
}

// ---------------------------------------------------------------- K5: scan pass A
// block = (b, chunk c), thread = d. 16 n-states in registers, dt_proj fused.
// Chunk decay product via P[n] = exp2(A2[n] * sum(dt)).
__global__ __launch_bounds__(256) void k_scanA(
    const float* __restrict__ dtr,   // (BL,8)
    const float* __restrict__ Wd,    // (256,8)
    const float* __restrict__ bd,    // (256)
    const float* __restrict__ xc,    // (BL,256)
    const float* __restrict__ Bm,    // (BL,16)
    const float* __restrict__ alog,  // (256,16)
    float* __restrict__ Pc, float* __restrict__ Sc)
{
  const int d  = threadIdx.x;
  const int cb = blockIdx.x;          // c*2+b
  const int b  = cb & 1, c = cb >> 1;
  const float LOG2E = 1.4426950408889634f;

  float A2[16];
  {
    const f32x4* al = (const f32x4*)(alog + (size_t)d * 16);
    #pragma unroll
    for (int q = 0; q < 4; ++q) {
      f32x4 v = al[q];
      #pragma unroll
      for (int j = 0; j < 4; ++j) A2[q * 4 + j] = -__expf(v[j]) * LOG2E;
    }
  }
  float wd[8];
  {
    const f32x4* wp = (const f32x4*)(Wd + (size_t)d * 8);
    f32x4 w0 = wp[0], w1 = wp[1];
    #pragma unroll
    for (int j = 0; j < 4; ++j) { wd[j] = w0[j]; wd[4 + j] = w1[j]; }
  }
  const float bdv = bd[d];

  float h[16];
  #pragma unroll
  for (int n = 0; n < 16; ++n) h[n] = 0.f;
  float Sdt = 0.f;

  size_t bl = (size_t)b * L + (size_t)c * CLEN;
  for (int tt = 0; tt < CLEN; ++tt, ++bl) {
    const f32x4* dr = (const f32x4*)(dtr + bl * 8);
    f32x4 r0 = dr[0], r1 = dr[1];
    float acc = bdv;
    #pragma unroll
    for (int j = 0; j < 4; ++j) acc += r0[j] * wd[j] + r1[j] * wd[4 + j];
    float dt = (acc > 20.f) ? acc : __logf(1.f + __expf(acc));
    float u  = dt * xc[bl * DI + d];
    const f32x4* bm = (const f32x4*)(Bm + bl * DS);
    f32x4 b0 = bm[0], b1 = bm[1], b2 = bm[2], b3 = bm[3];
    #pragma unroll
    for (int n = 0; n < 4; ++n) h[n]      = exp2f(dt * A2[n])      * h[n]      + u * b0[n];
    #pragma unroll
    for (int n = 0; n < 4; ++n) h[4 + n]  = exp2f(dt * A2[4 + n])  * h[4 + n]  + u * b1[n];
    #pragma unroll
    for (int n = 0; n < 4; ++n) h[8 + n]  = exp2f(dt * A2[8 + n])  * h[8 + n]  + u * b2[n];
    #pragma unroll
    for (int n = 0; n < 4; ++n) h[12 + n] = exp2f(dt * A2[12 + n]) * h[12 + n] + u * b3[n];
    Sdt += dt;
  }

  f32x4* pp = (f32x4*)(Pc + (((size_t)cb * 256) + d) * 16);
  f32x4* sp = (f32x4*)(Sc + (((size_t)cb * 256) + d) * 16);
  #pragma unroll
  for (int q = 0; q < 4; ++q) {
    f32x4 pv, sv;
    #pragma unroll
    for (int j = 0; j < 4; ++j) { pv[j] = exp2f(A2[q * 4 + j] * Sdt); sv[j] = h[q * 4 + j]; }
    pp[q] = pv; sp[q] = sv;
  }
}

// ---------------------------------------------------------------- K6: chunk-level scan
__global__ __launch_bounds__(256) void k_scanB(
    const float* __restrict__ Pc, const float* __restrict__ Sc, float* __restrict__ Hc)
{
  int t   = blockIdx.x * 256 + threadIdx.x;   // < 8192: b*4096 + (d*16+n)
  int b   = t >> 12;
  int loc = t & 4095;
  float h = 0.f;
  for (int c = 0; c < NCH; ++c) {
    size_t idx = ((size_t)(c * 2 + b)) * 4096 + loc;
    Hc[idx] = h;
    h = Pc[idx] * h + Sc[idx];
  }
}

// ---------------------------------------------------------------- K7: scan pass C (+ y, gate)
__global__ __launch_bounds__(256) void k_scanC(
    const float* __restrict__ dtr, const float* __restrict__ Wd, const float* __restrict__ bd,
    const float* __restrict__ xc,  const float* __restrict__ Bm, const float* __restrict__ Cm,
    const float* __restrict__ alog, const float* __restrict__ Dp, const float* __restrict__ z,
    const float* __restrict__ Hc, float* __restrict__ y)
{
  const int d  = threadIdx.x;
  const int cb = blockIdx.x;
  const int b  = cb & 1, c = cb >> 1;
  const float LOG2E = 1.4426950408889634f;

  float A2[16];
  {
    const f32x4* al = (const f32x4*)(alog + (size_t)d * 16);
    #pragma unroll
    for (int q = 0; q < 4; ++q) {
      f32x4 v = al[q];
      #pragma unroll
      for (int j = 0; j < 4; ++j) A2[q * 4 + j] = -__expf(v[j]) * LOG2E;
    }
  }
  float wd[8];
  {
    const f32x4* wp = (const f32x4*)(Wd + (size_t)d * 8);
    f32x4 w0 = wp[0], w1 = wp[1];
    #pragma unroll
    for (int j = 0; j < 4; ++j) { wd[j] = w0[j]; wd[4 + j] = w1[j]; }
  }
  const float bdv = bd[d];
  const float Dv  = Dp[d];

  float h[16];
  {
    const f32x4* hp = (const f32x4*)(Hc + (((size_t)cb * 256) + d) * 16);
    #pragma unroll
    for (int q = 0; q < 4; ++q) {
      f32x4 v = hp[q];
      #pragma unroll
      for (int j = 0; j < 4; ++j) h[q * 4 + j] = v[j];
    }
  }

  size_t bl = (size_t)b * L + (size_t)c * CLEN;
  for (int tt = 0; tt < CLEN; ++tt, ++bl) {
    const f32x4* dr = (const f32x4*)(dtr + bl * 8);
    f32x4 r0 = dr[0], r1 = dr[1];
    float acc = bdv;
    #pragma unroll
    for (int j = 0; j < 4; ++j) acc += r0[j] * wd[j] + r1[j] * wd[4 + j];
    float dt  = (acc > 20.f) ? acc : __logf(1.f + __expf(acc));
    float xcf = xc[bl * DI + d];
    float u   = dt * xcf;
    const f32x4* bm = (const f32x4*)(Bm + bl * DS);
    const f32x4* cm = (const f32x4*)(Cm + bl * DS);
    f32x4 b0 = bm[0], b1 = bm[1], b2 = bm[2], b3 = bm[3];
    f32x4 c0 = cm[0], c1 = cm[1], c2 = cm[2], c3 = cm[3];
    f32x4 py = {0.f, 0.f, 0.f, 0.f};
    #pragma unroll
    for (int n = 0; n < 4; ++n) { h[n]      = exp2f(dt * A2[n])      * h[n]      + u * b0[n]; py[n] += h[n]      * c0[n]; }
    #pragma unroll
    for (int n = 0; n < 4; ++n) { h[4 + n]  = exp2f(dt * A2[4 + n])  * h[4 + n]  + u * b1[n]; py[n] += h[4 + n]  * c1[n]; }
    #pragma unroll
    for (int n = 0; n < 4; ++n) { h[8 + n]  = exp2f(dt * A2[8 + n])  * h[8 + n]  + u * b2[n]; py[n] += h[8 + n]  * c2[n]; }
    #pragma unroll
    for (int n = 0; n < 4; ++n) { h[12 + n] = exp2f(dt * A2[12 + n]) * h[12 + n] + u * b3[n]; py[n] += h[12 + n] * c3[n]; }
    float ys = py[0] + py[1] + py[2] + py[3];
    float zf = z[bl * DI + d];
    float sil = zf / (1.f + __expf(-zf));
    y[bl * DI + d] = (ys + xcf * Dv) * sil;
  }
}

// ---------------------------------------------------------------- K8: out_proj + residual
__global__ __launch_bounds__(256) void k_outproj(
    const float* __restrict__ y,
    const float* __restrict__ W,    // (128,256)
    const float* __restrict__ x,    // (B,128,L)
    float* __restrict__ out)        // (B,128,L)
{
  const int wid  = (blockIdx.x * blockDim.x + threadIdx.x) >> 6;   // 0..999
  const int lane = threadIdx.x & 63;
  const int m = lane & 15, gq = lane >> 4;
  const int bl0 = wid * 16;
  const int b = (bl0 >= L) ? 1 : 0;
  const int lbase = bl0 - b * L;

  const float* bp = y + (size_t)(bl0 + m) * DI + gq * 8;
  short8 bfrag[8];
  #pragma unroll
  for (int f = 0; f < 8; ++f)
    #pragma unroll
    for (int j = 0; j < 8; ++j) bfrag[f][j] = f2bfs(bp[f * 32 + j]);

  for (int ct = 0; ct < 8; ++ct) {
    int c0 = ct * 16;
    const float* ap = W + (size_t)(c0 + m) * DI + gq * 8;
    f32x4 acc = {0.f, 0.f, 0.f, 0.f};
    #pragma unroll
    for (int f = 0; f < 8; ++f) {
      short8 a;
      #pragma unroll
      for (int j = 0; j < 8; ++j) a[j] = f2bfs(ap[f * 32 + j]);
      acc = __builtin_amdgcn_mfma_f32_16x16x32_bf16(a, bfrag[f], acc, 0, 0, 0);
    }
    #pragma unroll
    for (int r = 0; r < 4; ++r) {
      int cc = c0 + gq * 4 + r;
      size_t o = ((size_t)b * DIM + cc) * L + lbase + m;
      out[o] = x[o] + acc[r];
    }
  }
}

// ----------------------------------------------------------------
extern "C" void kernel_launch(void* const* d_in, const int* in_sizes, int n_in,
                              void* d_out, int out_size, void* d_ws, size_t ws_size,
                              hipStream_t stream)
{
  const float* x      = (const float*)d_in[0];
  const float* gamma  = (const float*)d_in[1];
  const float* beta   = (const float*)d_in[2];
  const float* inW    = (const float*)d_in[3];
  const float* convW  = (const float*)d_in[4];
  const float* convB  = (const float*)d_in[5];
  const float* xprojW = (const float*)d_in[6];
  const float* dtW    = (const float*)d_in[7];
  const float* dtB    = (const float*)d_in[8];
  const float* Alog   = (const float*)d_in[9];
  const float* Dp     = (const float*)d_in[10];
  const float* outW   = (const float*)d_in[11];
  float* out = (float*)d_out;

  char* ws = (char*)d_ws;
  float* xi  = (float*)(ws + 0);            // BL*256 f32 = 16,384,000
  float* z   = (float*)(ws + 16384000);     // BL*256 f32
  float* xc  = (float*)(ws + 32768000);     // BL*256 f32
  float* dtr = (float*)(ws + 49152000);     // BL*8  f32 =    512,000
  float* Bm  = (float*)(ws + 49664000);     // BL*16 f32 =  1,024,000
  float* Cm  = (float*)(ws + 50688000);     // BL*16 f32 =  1,024,000
  float* yb  = (float*)(ws + 51712000);     // BL*256 f32 = 16,384,000
  float* Pc  = (float*)(ws + 68096000);     // 2*NCH*4096 f32 = 6,553,600
  float* Sc  = (float*)(ws + 74649600);     // 6,553,600
  float* Hc  = (float*)(ws + 81203200);     // 6,553,600 -> end 87,756,800 B

  hipLaunchKernelGGL(k_ln_inproj, dim3(250),     dim3(256), 0, stream, x, gamma, beta, inW, xi, z);
  hipLaunchKernelGGL(k_conv,      dim3(16000),   dim3(256), 0, stream, xi, convW, convB, xc);
  hipLaunchKernelGGL(k_xproj,     dim3(250),     dim3(256), 0, stream, xc, xprojW, dtr, Bm, Cm);
  hipLaunchKernelGGL(k_scanA,     dim3(2 * NCH), dim3(256), 0, stream, dtr, dtW, dtB, xc, Bm, Alog, Pc, Sc);
  hipLaunchKernelGGL(k_scanB,     dim3(32),      dim3(256), 0, stream, Pc, Sc, Hc);
  hipLaunchKernelGGL(k_scanC,     dim3(2 * NCH), dim3(256), 0, stream, dtr, dtW, dtB, xc, Bm, Cm, Alog, Dp, z, Hc, yb);
  hipLaunchKernelGGL(k_outproj,   dim3(250),     dim3(256), 0, stream, yb, outW, x, out);
}

// Round 4
// 171.588 us; speedup vs baseline: 1.6016x; 1.1524x over previous
//
#include <hip/hip_runtime.h>

typedef short short8 __attribute__((ext_vector_type(8)));
typedef float f32x4 __attribute__((ext_vector_type(4)));

#define DEVFN __device__ __forceinline__

DEVFN float bf2f(unsigned short u) {
  union { unsigned int i; float f; } c; c.i = ((unsigned int)u) << 16; return c.f;
}
DEVFN unsigned short f2bf(float f) {
  union { float f; unsigned int i; } c; c.f = f;
  unsigned int r = c.i + 0x7FFFu + ((c.i >> 16) & 1u);
  return (unsigned short)(r >> 16);
}
DEVFN short f2bfs(float f) { return (short)f2bf(f); }

static constexpr int Bn  = 2;
static constexpr int L   = 8000;
static constexpr int BL  = Bn * L;     // 16000
static constexpr int DIM = 128;
static constexpr int DI  = 256;        // d_inner
static constexpr int DS  = 16;         // d_state
static constexpr int CLEN = 40;        // chunk length
static constexpr int NCH  = 200;       // chunks per sequence

// ---------------------------------------------------------------- K0: f32 -> bf16 weight conversion
__global__ __launch_bounds__(256) void k_cvt(const float* __restrict__ s,
                                             unsigned short* __restrict__ dst, int n) {
  int i = blockIdx.x * 256 + threadIdx.x;
  if (i < n) dst[i] = f2bf(s[i]);
}

// ---------------------------------------------------------------- K1: LN + in_proj
__global__ __launch_bounds__(256) void k_ln_inproj(
    const float* __restrict__ x,      // (B,128,L)
    const float* __restrict__ gamma,
    const float* __restrict__ beta,
    const unsigned short* __restrict__ W,   // (512,128) bf16
    float* __restrict__ xi,           // (BL,256) f32
    unsigned short* __restrict__ z)   // (BL,256) bf16
{
  const int wid  = (blockIdx.x * blockDim.x + threadIdx.x) >> 6;   // 0..999
  const int lane = threadIdx.x & 63;
  const int m  = lane & 15;
  const int gq = lane >> 4;
  const int bl0 = wid * 16;
  const int bl  = bl0 + m;
  const int b   = (bl >= L) ? 1 : 0;
  const int l   = bl - b * L;
  const float* xb = x + (size_t)b * DIM * L + l;

  float v[32];
  float s = 0.f, s2 = 0.f;
  #pragma unroll
  for (int f = 0; f < 4; ++f)
    #pragma unroll
    for (int j = 0; j < 8; ++j) {
      int k = f * 32 + gq * 8 + j;
      float t = xb[(size_t)k * L];
      v[f * 8 + j] = t; s += t; s2 += t * t;
    }
  s  += __shfl_xor(s, 16);  s  += __shfl_xor(s, 32);
  s2 += __shfl_xor(s2, 16); s2 += __shfl_xor(s2, 32);
  float mu   = s * (1.f / 128.f);
  float var  = s2 * (1.f / 128.f) - mu * mu;
  float rstd = rsqrtf(var + 1e-5f);

  short8 a[4];
  #pragma unroll
  for (int f = 0; f < 4; ++f)
    #pragma unroll
    for (int j = 0; j < 8; ++j) {
      int k = f * 32 + gq * 8 + j;
      float xn = (v[f * 8 + j] - mu) * rstd * gamma[k] + beta[k];
      a[f][j] = f2bfs(xn);
    }

  for (int nt = 0; nt < 32; ++nt) {
    int n0 = nt * 16;
    const unsigned short* wr = W + (size_t)(n0 + m) * DIM + gq * 8;
    f32x4 acc = {0.f, 0.f, 0.f, 0.f};
    #pragma unroll
    for (int f = 0; f < 4; ++f) {
      short8 bfr = *(const short8*)(wr + f * 32);
      acc = __builtin_amdgcn_mfma_f32_16x16x32_bf16(a[f], bfr, acc, 0, 0, 0);
    }
    int ng = n0 + m;
    #pragma unroll
    for (int r = 0; r < 4; ++r) {
      int row = bl0 + gq * 4 + r;
      if (n0 < DI) xi[(size_t)row * DI + ng]        = acc[r];
      else         z [(size_t)row * DI + (ng - DI)] = f2bf(acc[r]);
    }
  }
}

// ---------------------------------------------------------------- K2: causal depthwise conv + SiLU
__global__ __launch_bounds__(256) void k_conv(
    const float* __restrict__ xi,
    const float* __restrict__ cw,   // (256,1,4)
    const float* __restrict__ cb,
    float* __restrict__ xc)
{
  int idx = blockIdx.x * 256 + threadIdx.x;   // bl*256 + d
  int d  = idx & 255;
  int bl = idx >> 8;
  int b  = (bl >= L) ? 1 : 0;
  int l  = bl - b * L;
  float acc = cb[d];
  #pragma unroll
  for (int t = 0; t < 4; ++t) {
    int ll = l - 3 + t;
    if (ll >= 0)
      acc += cw[d * 4 + t] * xi[((size_t)(b * L + ll)) * DI + d];
  }
  float sig = 1.f / (1.f + __expf(-acc));
  xc[idx] = acc * sig;
}

// ---------------------------------------------------------------- K3: x_proj (N=40, padded to 48)
__global__ __launch_bounds__(256) void k_xproj(
    const float* __restrict__ xc,
    const unsigned short* __restrict__ W,  // (40,256) bf16
    float* __restrict__ dtr,        // (BL,8)
    float* __restrict__ Bm,         // (BL,16)
    float* __restrict__ Cm)         // (BL,16)
{
  const int wid  = (blockIdx.x * blockDim.x + threadIdx.x) >> 6;
  const int lane = threadIdx.x & 63;
  const int m = lane & 15, gq = lane >> 4;
  const int bl0 = wid * 16;
  const float* ap = xc + (size_t)(bl0 + m) * DI + gq * 8;
  short8 a[8];
  #pragma unroll
  for (int f = 0; f < 8; ++f)
    #pragma unroll
    for (int j = 0; j < 8; ++j) a[f][j] = f2bfs(ap[f * 32 + j]);

  #pragma unroll
  for (int nt = 0; nt < 3; ++nt) {
    int n0 = nt * 16;
    int n  = n0 + m;
    f32x4 acc = {0.f, 0.f, 0.f, 0.f};
    const unsigned short* wr = W + (size_t)n * DI + gq * 8;
    #pragma unroll
    for (int f = 0; f < 8; ++f) {
      short8 bfr = {0,0,0,0,0,0,0,0};
      if (n < 40) bfr = *(const short8*)(wr + f * 32);
      acc = __builtin_amdgcn_mfma_f32_16x16x32_bf16(a[f], bfr, acc, 0, 0, 0);
    }
    #pragma unroll
    for (int r = 0; r < 4; ++r) {
      int row = bl0 + gq * 4 + r;
      if (n < 8)       dtr[(size_t)row * 8  + n]        = acc[r];
      else if (n < 24) Bm [(size_t)row * 16 + (n - 8)]  = acc[r];
      else if (n < 40) Cm [(size_t)row * 16 + (n - 24)] = acc[r];
    }
  }
}

// ---------------------------------------------------------------- K5: scan pass A
// block = (b,c), 512 threads: thread = 2*d + half, 8 n-states each. dt_proj fused.
__global__ __launch_bounds__(512) void k_scanA(
    const float* __restrict__ dtr,   // (BL,8)
    const float* __restrict__ Wd,    // (256,8)
    const float* __restrict__ bd,    // (256)
    const float* __restrict__ xc,    // (BL,256)
    const float* __restrict__ Bm,    // (BL,16)
    const float* __restrict__ alog,  // (256,16)
    float* __restrict__ Pc, float* __restrict__ Sc)
{
  const int t    = threadIdx.x;
  const int d    = t >> 1, half = t & 1;
  const int cb   = blockIdx.x;          // c*2+b
  const int b    = cb & 1, c = cb >> 1;
  const float LOG2E = 1.4426950408889634f;

  float A2[8];
  {
    const f32x4* al = (const f32x4*)(alog + (size_t)d * 16 + half * 8);
    #pragma unroll
    for (int q = 0; q < 2; ++q) {
      f32x4 v = al[q];
      #pragma unroll
      for (int j = 0; j < 4; ++j) A2[q * 4 + j] = -__expf(v[j]) * LOG2E;
    }
  }
  float wd[8];
  {
    const f32x4* wp = (const f32x4*)(Wd + (size_t)d * 8);
    f32x4 w0 = wp[0], w1 = wp[1];
    #pragma unroll
    for (int j = 0; j < 4; ++j) { wd[j] = w0[j]; wd[4 + j] = w1[j]; }
  }
  const float bdv = bd[d];

  float h[8];
  #pragma unroll
  for (int n = 0; n < 8; ++n) h[n] = 0.f;
  float Sdt = 0.f;

  size_t bl = (size_t)b * L + (size_t)c * CLEN;
  for (int tt = 0; tt < CLEN; ++tt, ++bl) {
    const f32x4* dr = (const f32x4*)(dtr + bl * 8);
    f32x4 r0 = dr[0], r1 = dr[1];
    float acc = bdv;
    #pragma unroll
    for (int j = 0; j < 4; ++j) acc += r0[j] * wd[j] + r1[j] * wd[4 + j];
    float dt = (acc > 20.f) ? acc : __logf(1.f + __expf(acc));
    float u  = dt * xc[bl * DI + d];
    const f32x4* bm = (const f32x4*)(Bm + bl * DS + half * 8);
    f32x4 b0 = bm[0], b1 = bm[1];
    #pragma unroll
    for (int n = 0; n < 4; ++n) h[n]     = exp2f(dt * A2[n])     * h[n]     + u * b0[n];
    #pragma unroll
    for (int n = 0; n < 4; ++n) h[4 + n] = exp2f(dt * A2[4 + n]) * h[4 + n] + u * b1[n];
    Sdt += dt;
  }

  f32x4* pp = (f32x4*)(Pc + (size_t)cb * 4096 + d * 16 + half * 8);
  f32x4* sp = (f32x4*)(Sc + (size_t)cb * 4096 + d * 16 + half * 8);
  #pragma unroll
  for (int q = 0; q < 2; ++q) {
    f32x4 pv, sv;
    #pragma unroll
    for (int j = 0; j < 4; ++j) { pv[j] = exp2f(A2[q * 4 + j] * Sdt); sv[j] = h[q * 4 + j]; }
    pp[q] = pv; sp[q] = sv;
  }
}

// ---------------------------------------------------------------- K6: chunk-level scan (pipelined)
__global__ __launch_bounds__(64) void k_scanB(
    const float* __restrict__ Pc, const float* __restrict__ Sc, float* __restrict__ Hc)
{
  int t   = blockIdx.x * 64 + threadIdx.x;   // < 8192: b*4096 + (d*16+n)
  int b   = t >> 12;
  int loc = t & 4095;
  float h = 0.f;
  for (int c0 = 0; c0 < NCH; c0 += 20) {
    float p[20], s[20];
    #pragma unroll
    for (int i = 0; i < 20; ++i) {
      size_t idx = ((size_t)((c0 + i) * 2 + b)) * 4096 + loc;
      p[i] = Pc[idx]; s[i] = Sc[idx];
    }
    #pragma unroll
    for (int i = 0; i < 20; ++i) {
      size_t idx = ((size_t)((c0 + i) * 2 + b)) * 4096 + loc;
      Hc[idx] = h;
      h = p[i] * h + s[i];
    }
  }
}

// ---------------------------------------------------------------- K7: scan pass C (+ y, gate)
__global__ __launch_bounds__(512) void k_scanC(
    const float* __restrict__ dtr, const float* __restrict__ Wd, const float* __restrict__ bd,
    const float* __restrict__ xc,  const float* __restrict__ Bm, const float* __restrict__ Cm,
    const float* __restrict__ alog, const float* __restrict__ Dp,
    const unsigned short* __restrict__ z,
    const float* __restrict__ Hc,
    unsigned short* __restrict__ y)          // (BL,256) bf16
{
  const int t    = threadIdx.x;
  const int d    = t >> 1, half = t & 1;
  const int cb   = blockIdx.x;
  const int b    = cb & 1, c = cb >> 1;
  const float LOG2E = 1.4426950408889634f;

  float A2[8];
  {
    const f32x4* al = (const f32x4*)(alog + (size_t)d * 16 + half * 8);
    #pragma unroll
    for (int q = 0; q < 2; ++q) {
      f32x4 v = al[q];
      #pragma unroll
      for (int j = 0; j < 4; ++j) A2[q * 4 + j] = -__expf(v[j]) * LOG2E;
    }
  }
  float wd[8];
  {
    const f32x4* wp = (const f32x4*)(Wd + (size_t)d * 8);
    f32x4 w0 = wp[0], w1 = wp[1];
    #pragma unroll
    for (int j = 0; j < 4; ++j) { wd[j] = w0[j]; wd[4 + j] = w1[j]; }
  }
  const float bdv = bd[d];
  const float Dv  = Dp[d];

  float h[8];
  {
    const f32x4* hp = (const f32x4*)(Hc + (size_t)cb * 4096 + d * 16 + half * 8);
    f32x4 v0 = hp[0], v1 = hp[1];
    #pragma unroll
    for (int j = 0; j < 4; ++j) { h[j] = v0[j]; h[4 + j] = v1[j]; }
  }

  size_t bl = (size_t)b * L + (size_t)c * CLEN;
  for (int tt = 0; tt < CLEN; ++tt, ++bl) {
    const f32x4* dr = (const f32x4*)(dtr + bl * 8);
    f32x4 r0 = dr[0], r1 = dr[1];
    float acc = bdv;
    #pragma unroll
    for (int j = 0; j < 4; ++j) acc += r0[j] * wd[j] + r1[j] * wd[4 + j];
    float dt  = (acc > 20.f) ? acc : __logf(1.f + __expf(acc));
    float xcf = xc[bl * DI + d];
    float u   = dt * xcf;
    const f32x4* bm = (const f32x4*)(Bm + bl * DS + half * 8);
    const f32x4* cm = (const f32x4*)(Cm + bl * DS + half * 8);
    f32x4 b0 = bm[0], b1 = bm[1];
    f32x4 c0 = cm[0], c1 = cm[1];
    f32x4 py = {0.f, 0.f, 0.f, 0.f};
    #pragma unroll
    for (int n = 0; n < 4; ++n) { h[n]     = exp2f(dt * A2[n])     * h[n]     + u * b0[n]; py[n] += h[n]     * c0[n]; }
    #pragma unroll
    for (int n = 0; n < 4; ++n) { h[4 + n] = exp2f(dt * A2[4 + n]) * h[4 + n] + u * b1[n]; py[n] += h[4 + n] * c1[n]; }
    float ys = (py[0] + py[1]) + (py[2] + py[3]);
    ys += __shfl_xor(ys, 1);
    if (half == 0) {
      float zf  = bf2f(z[bl * DI + d]);
      float sil = zf / (1.f + __expf(-zf));
      y[bl * DI + d] = f2bf((ys + xcf * Dv) * sil);
    }
  }
}

// ---------------------------------------------------------------- K8: out_proj + residual
__global__ __launch_bounds__(256) void k_outproj(
    const unsigned short* __restrict__ y,  // (BL,256) bf16
    const unsigned short* __restrict__ W,  // (128,256) bf16
    const float* __restrict__ x,    // (B,128,L)
    float* __restrict__ out)        // (B,128,L)
{
  const int wid  = (blockIdx.x * blockDim.x + threadIdx.x) >> 6;   // 0..999
  const int lane = threadIdx.x & 63;
  const int m = lane & 15, gq = lane >> 4;
  const int bl0 = wid * 16;
  const int b = (bl0 >= L) ? 1 : 0;
  const int lbase = bl0 - b * L;

  const unsigned short* bp = y + (size_t)(bl0 + m) * DI + gq * 8;
  short8 bfrag[8];
  #pragma unroll
  for (int f = 0; f < 8; ++f) bfrag[f] = *(const short8*)(bp + f * 32);

  for (int ct = 0; ct < 8; ++ct) {
    int c0 = ct * 16;
    const unsigned short* ap = W + (size_t)(c0 + m) * DI + gq * 8;
    f32x4 acc = {0.f, 0.f, 0.f, 0.f};
    #pragma unroll
    for (int f = 0; f < 8; ++f) {
      short8 a = *(const short8*)(ap + f * 32);
      acc = __builtin_amdgcn_mfma_f32_16x16x32_bf16(a, bfrag[f], acc, 0, 0, 0);
    }
    #pragma unroll
    for (int r = 0; r < 4; ++r) {
      int cc = c0 + gq * 4 + r;
      size_t o = ((size_t)b * DIM + cc) * L + lbase + m;
      out[o] = x[o] + acc[r];
    }
  }
}

// ----------------------------------------------------------------
extern "C" void kernel_launch(void* const* d_in, const int* in_sizes, int n_in,
                              void* d_out, int out_size, void* d_ws, size_t ws_size,
                              hipStream_t stream)
{
  const float* x      = (const float*)d_in[0];
  const float* gamma  = (const float*)d_in[1];
  const float* beta   = (const float*)d_in[2];
  const float* inW    = (const float*)d_in[3];
  const float* convW  = (const float*)d_in[4];
  const float* convB  = (const float*)d_in[5];
  const float* xprojW = (const float*)d_in[6];
  const float* dtW    = (const float*)d_in[7];
  const float* dtB    = (const float*)d_in[8];
  const float* Alog   = (const float*)d_in[9];
  const float* Dp     = (const float*)d_in[10];
  const float* outW   = (const float*)d_in[11];
  float* out = (float*)d_out;

  char* ws = (char*)d_ws;
  float*          xi   = (float*)(ws + 0);            // 16,384,000
  float*          xc   = (float*)(ws + 16384000);     // 16,384,000
  unsigned short* z    = (unsigned short*)(ws + 32768000);  // 8,192,000
  unsigned short* yb   = (unsigned short*)(ws + 40960000);  // 8,192,000
  float*          dtr  = (float*)(ws + 49152000);     //    512,000
  float*          Bm   = (float*)(ws + 49664000);     //  1,024,000
  float*          Cm   = (float*)(ws + 50688000);     //  1,024,000
  float*          Pc   = (float*)(ws + 51712000);     //  6,553,600
  float*          Sc   = (float*)(ws + 58265600);     //  6,553,600
  float*          Hc   = (float*)(ws + 64819200);     //  6,553,600
  unsigned short* Wbi  = (unsigned short*)(ws + 71372800);  //   131,072
  unsigned short* Wbx  = (unsigned short*)(ws + 71503872);  //    20,480
  unsigned short* Wbo  = (unsigned short*)(ws + 71524352);  //    65,536 -> end 71,589,888

  hipLaunchKernelGGL(k_cvt, dim3(256), dim3(256), 0, stream, inW,   Wbi, 512 * 128);
  hipLaunchKernelGGL(k_cvt, dim3(40),  dim3(256), 0, stream, xprojW, Wbx, 40 * 256);
  hipLaunchKernelGGL(k_cvt, dim3(128), dim3(256), 0, stream, outW,  Wbo, 128 * 256);

  hipLaunchKernelGGL(k_ln_inproj, dim3(250),     dim3(256), 0, stream, x, gamma, beta, Wbi, xi, z);
  hipLaunchKernelGGL(k_conv,      dim3(16000),   dim3(256), 0, stream, xi, convW, convB, xc);
  hipLaunchKernelGGL(k_xproj,     dim3(250),     dim3(256), 0, stream, xc, Wbx, dtr, Bm, Cm);
  hipLaunchKernelGGL(k_scanA,     dim3(2 * NCH), dim3(512), 0, stream, dtr, dtW, dtB, xc, Bm, Alog, Pc, Sc);
  hipLaunchKernelGGL(k_scanB,     dim3(128),     dim3(64),  0, stream, Pc, Sc, Hc);
  hipLaunchKernelGGL(k_scanC,     dim3(2 * NCH), dim3(512), 0, stream, dtr, dtW, dtB, xc, Bm, Cm, Alog, Dp, z, Hc, yb);
  hipLaunchKernelGGL(k_outproj,   dim3(250),     dim3(256), 0, stream, yb, Wbo, x, out);
}